// Round 21
// baseline (242.311 us; speedup 1.0000x reference)
//
#include <hip/hip_runtime.h>

typedef _Float16 half8  __attribute__((ext_vector_type(8)));
typedef _Float16 half4v __attribute__((ext_vector_type(4)));
typedef _Float16 half2v __attribute__((ext_vector_type(2)));
typedef float    floatx4 __attribute__((ext_vector_type(4)));
typedef float    float2v __attribute__((ext_vector_type(2)));

static constexpr float INVPI = 0.3183098861837907f;  // weights pre-scaled by 1/pi:
static constexpr float RLOG  = 3.82843f;             // MFMA emits 2*theta in revolutions

// Fused activation via double-angle (R16): h = E + c2*(F + G*c2), c2=cos(2theta).
// Tail in packed f16 (R20-verified: v_pk_fma_f16 via builtin; the f32
// v_pk_fma_f32 inline-asm path failed numerically twice (R17/R18) - banned).
static constexpr double RD = (double)RLOG;
static constexpr double AD = RD*RD/4.0 - RD*RD*RD/16.0;
static constexpr double BD = -RD*RD/4.0 + RD*RD*RD/8.0;
static constexpr double DD = -RD*RD*RD/16.0;
static constexpr float ACT_E = (float)(AD + BD/2.0 + DD/4.0);   //  0.955347
static constexpr float ACT_F = (float)((BD + DD)/2.0);          // -0.078584
static constexpr float ACT_G = (float)(DD/4.0);                 // -0.876763

__device__ __forceinline__ float act_rev(float a2) {   // f32: final output only
    float c = __builtin_amdgcn_cosf(a2);
    float t = __builtin_fmaf(ACT_G, c, ACT_F);
    return __builtin_fmaf(c, t, ACT_E);
}

// Two C-frags (tiles t, t+2) -> next-layer B-frag directly.
// Per 8 values: 8 v_cos + 4 cvt_pkrtz + 8 v_pk_fma_f16.
__device__ __forceinline__ half8 act8(floatx4 a, floatx4 b) {
    const half2v Gh = {(_Float16)ACT_G, (_Float16)ACT_G};
    const half2v Fh = {(_Float16)ACT_F, (_Float16)ACT_F};
    const half2v Eh = {(_Float16)ACT_E, (_Float16)ACT_E};
    half2v c0 = __builtin_bit_cast(half2v, __builtin_amdgcn_cvt_pkrtz(
                    __builtin_amdgcn_cosf(a[0]), __builtin_amdgcn_cosf(a[1])));
    half2v c1 = __builtin_bit_cast(half2v, __builtin_amdgcn_cvt_pkrtz(
                    __builtin_amdgcn_cosf(a[2]), __builtin_amdgcn_cosf(a[3])));
    half2v c2 = __builtin_bit_cast(half2v, __builtin_amdgcn_cvt_pkrtz(
                    __builtin_amdgcn_cosf(b[0]), __builtin_amdgcn_cosf(b[1])));
    half2v c3 = __builtin_bit_cast(half2v, __builtin_amdgcn_cvt_pkrtz(
                    __builtin_amdgcn_cosf(b[2]), __builtin_amdgcn_cosf(b[3])));
    half2v t0 = __builtin_elementwise_fma(c0, Gh, Fh);
    half2v t1 = __builtin_elementwise_fma(c1, Gh, Fh);
    half2v t2 = __builtin_elementwise_fma(c2, Gh, Fh);
    half2v t3 = __builtin_elementwise_fma(c3, Gh, Fh);
    half2v h0 = __builtin_elementwise_fma(c0, t0, Eh);
    half2v h1 = __builtin_elementwise_fma(c1, t1, Eh);
    half2v h2 = __builtin_elementwise_fma(c2, t2, Eh);
    half2v h3 = __builtin_elementwise_fma(c3, t3, Eh);
    half4v lo = __builtin_shufflevector(h0, h1, 0, 1, 2, 3);
    half4v hi = __builtin_shufflevector(h2, h3, 0, 1, 2, 3);
    return __builtin_shufflevector(lo, hi, 0, 1, 2, 3, 4, 5, 6, 7);
}

// Per-block LDS weight cache (R9/R11-proven; biases stay in LDS -- R12
// showed biases-in-regs spill at the (512,8) 64-reg cap).
// 2-tile jam (on the R20 base): doubles the independent mfma->cos->fma
// chains per wave (fills the 35% latency-stall R20 left) and CSEs all LDS
// frag reads across the two tiles (24 -> 12 reads/tile).
struct SMem {
    half8   w2[8][64];   // [(t*2+c)][lane]
    half8   w3[8][64];
    floatx4 b2[4][64];   // [t][lane]
    floatx4 b3[4][64];
};

__global__ __launch_bounds__(512, 8) void mlp_fused(
    const float* __restrict__ x,
    const float* __restrict__ W1, const float* __restrict__ b1,
    const float* __restrict__ W2, const float* __restrict__ b2,
    const float* __restrict__ W3, const float* __restrict__ b3,
    const float* __restrict__ W4, const float* __restrict__ b4,
    float* __restrict__ out, int N)
{
    __shared__ SMem sm;
    const int lane = threadIdx.x & 63;
    const int wib  = threadIdx.x >> 6;   // 0..7
    const int m    = lane & 15;   // sample / C col / A row
    const int q    = lane >> 4;   // quad
    const float s  = INVPI;      // all layers: 1/pi scaling (double-angle form)
    const floatx4 zero4 = {0.0f, 0.0f, 0.0f, 0.0f};

    // ---- in-register persistent frags (small): L1 and L4 ----
    // L1 A-frag (tile t), lanes q==0: [w0h, w0h, w0l, w1h, w1h, w1l, b1h, b1l]
    half8 w1f[4];
    #pragma unroll
    for (int t = 0; t < 4; ++t) {
        half8 v = {};
        if (q == 0) {
            const int n = 16 * t + m;
            float w0 = W1[2*n] * s, w1 = W1[2*n+1] * s, bb = b1[n] * s;
            _Float16 w0h = (_Float16)w0; float w0l = w0 - (float)w0h;
            _Float16 w1h = (_Float16)w1; float w1l = w1 - (float)w1h;
            _Float16 bh  = (_Float16)bb; float bl  = bb - (float)bh;
            v[0] = w0h; v[1] = w0h; v[2] = (_Float16)w0l;
            v[3] = w1h; v[4] = w1h; v[5] = (_Float16)w1l;
            v[6] = bh;  v[7] = (_Float16)bl;
        }
        w1f[t] = v;
    }
    // L4 A-frag: only out-row m==0 real; sigma column permutation
    //   sigma: k-slot (c,q,j) -> neuron (j<4 ? 16c+4q+j : 16(c+2)+4q+j-4)
    half8 w4f[2] = {half8{}, half8{}};
    if (m == 0) {
        #pragma unroll
        for (int c = 0; c < 2; ++c)
            #pragma unroll
            for (int j = 0; j < 8; ++j) {
                int nu = (j < 4) ? (16 * c + 4 * q + j) : (16 * (c + 2) + 4 * q + j - 4);
                w4f[c][j] = (_Float16)(W4[nu] * s);
            }
    }
    floatx4 a4init = zero4;
    if (q == 0) a4init[0] = b4[0] * s;       // C row 0 = (q=0, r=0)

    // ---- wave-split LDS prep (sigma-permuted columns), one barrier ----
    if (wib == 0) {
        #pragma unroll
        for (int t = 0; t < 4; ++t) {
            const float* r2 = W2 + (16 * t + m) * 64;
            #pragma unroll
            for (int c = 0; c < 2; ++c) {
                floatx4 lo2 = *(const floatx4*)(r2 + 16 * c + 4 * q);
                floatx4 hi2 = *(const floatx4*)(r2 + 16 * (c + 2) + 4 * q);
                half8 v2;
                #pragma unroll
                for (int j = 0; j < 4; ++j) {
                    v2[j]     = (_Float16)(lo2[j] * s);
                    v2[4 + j] = (_Float16)(hi2[j] * s);
                }
                sm.w2[t * 2 + c][lane] = v2;
            }
        }
    } else if (wib == 1) {
        #pragma unroll
        for (int t = 0; t < 4; ++t) {
            const float* r3 = W3 + (16 * t + m) * 64;
            #pragma unroll
            for (int c = 0; c < 2; ++c) {
                floatx4 lo3 = *(const floatx4*)(r3 + 16 * c + 4 * q);
                floatx4 hi3 = *(const floatx4*)(r3 + 16 * (c + 2) + 4 * q);
                half8 v3;
                #pragma unroll
                for (int j = 0; j < 4; ++j) {
                    v3[j]     = (_Float16)(lo3[j] * s);
                    v3[4 + j] = (_Float16)(hi3[j] * s);
                }
                sm.w3[t * 2 + c][lane] = v3;
            }
        }
    } else if (wib == 2) {
        #pragma unroll
        for (int t = 0; t < 4; ++t) {
            sm.b2[t][lane] = *(const floatx4*)(b2 + 16 * t + 4 * q) * s;
            sm.b3[t][lane] = *(const floatx4*)(b3 + 16 * t + 4 * q) * s;
        }
    }
    __syncthreads();

    const int npairs = N >> 5;               // pairs of 16-row tiles
    const int nwaves = (gridDim.x * blockDim.x) >> 6;
    const int gwave  = (int)(blockIdx.x * blockDim.x + threadIdx.x) >> 6;
    const float2* __restrict__ x2 = (const float2*)x;

    int pair = gwave;
    float2 xv0 = x2[(pair << 5) + m];
    float2 xv1 = x2[(pair << 5) + 16 + m];
    while (pair < npairs) {
        const int np = pair + nwaves;
        float2 xn0, xn1;
        if (np < npairs) {
            xn0 = x2[(np << 5) + m];
            xn1 = x2[(np << 5) + 16 + m];
        }

        // L1 B-frags (lanes q==0): [xh, xl, xh, yh, yl, yh, 1, 1]
        half8 xa[2] = {half8{}, half8{}};
        if (q == 0) {
            float2 xs[2] = {xv0, xv1};
            #pragma unroll
            for (int u = 0; u < 2; ++u) {
                _Float16 xh = (_Float16)xs[u].x; float xl = xs[u].x - (float)xh;
                _Float16 yh = (_Float16)xs[u].y; float yl = xs[u].y - (float)yh;
                xa[u][0] = xh; xa[u][1] = (_Float16)xl; xa[u][2] = xh;
                xa[u][3] = yh; xa[u][4] = (_Float16)yl; xa[u][5] = yh;
                xa[u][6] = (_Float16)1.0f; xa[u][7] = (_Float16)1.0f;
            }
        }

        // ---- layer 1 (two independent chains) ----
        half8 B0[2], B1[2];
        #pragma unroll
        for (int u = 0; u < 2; ++u) {
            floatx4 a0 = __builtin_amdgcn_mfma_f32_16x16x32_f16(w1f[0], xa[u], zero4, 0, 0, 0);
            floatx4 a1 = __builtin_amdgcn_mfma_f32_16x16x32_f16(w1f[1], xa[u], zero4, 0, 0, 0);
            floatx4 a2 = __builtin_amdgcn_mfma_f32_16x16x32_f16(w1f[2], xa[u], zero4, 0, 0, 0);
            floatx4 a3 = __builtin_amdgcn_mfma_f32_16x16x32_f16(w1f[3], xa[u], zero4, 0, 0, 0);
            B0[u] = act8(a0, a2);
            B1[u] = act8(a1, a3);
        }

        // Opaque zero per layer: defeats LICM (hoisted LDS reads would become
        // ~96 live regs and spill); frag reads shared by both u-chains.
        int z2 = 0; asm volatile("" : "+v"(z2));
        const int l2i = lane + z2;
        half8 C0[2], C1[2];
        #pragma unroll
        for (int u = 0; u < 2; ++u) {
            floatx4 a0 = __builtin_amdgcn_mfma_f32_16x16x32_f16(sm.w2[0][l2i], B0[u], sm.b2[0][l2i], 0, 0, 0);
            floatx4 a1 = __builtin_amdgcn_mfma_f32_16x16x32_f16(sm.w2[2][l2i], B0[u], sm.b2[1][l2i], 0, 0, 0);
            floatx4 a2 = __builtin_amdgcn_mfma_f32_16x16x32_f16(sm.w2[4][l2i], B0[u], sm.b2[2][l2i], 0, 0, 0);
            floatx4 a3 = __builtin_amdgcn_mfma_f32_16x16x32_f16(sm.w2[6][l2i], B0[u], sm.b2[3][l2i], 0, 0, 0);
            a0 = __builtin_amdgcn_mfma_f32_16x16x32_f16(sm.w2[1][l2i], B1[u], a0, 0, 0, 0);
            a1 = __builtin_amdgcn_mfma_f32_16x16x32_f16(sm.w2[3][l2i], B1[u], a1, 0, 0, 0);
            a2 = __builtin_amdgcn_mfma_f32_16x16x32_f16(sm.w2[5][l2i], B1[u], a2, 0, 0, 0);
            a3 = __builtin_amdgcn_mfma_f32_16x16x32_f16(sm.w2[7][l2i], B1[u], a3, 0, 0, 0);
            C0[u] = act8(a0, a2);
            C1[u] = act8(a1, a3);
        }

        int z3 = 0; asm volatile("" : "+v"(z3));
        const int l3i = lane + z3;
        half8 D0[2], D1[2];
        #pragma unroll
        for (int u = 0; u < 2; ++u) {
            floatx4 a0 = __builtin_amdgcn_mfma_f32_16x16x32_f16(sm.w3[0][l3i], C0[u], sm.b3[0][l3i], 0, 0, 0);
            floatx4 a1 = __builtin_amdgcn_mfma_f32_16x16x32_f16(sm.w3[2][l3i], C0[u], sm.b3[1][l3i], 0, 0, 0);
            floatx4 a2 = __builtin_amdgcn_mfma_f32_16x16x32_f16(sm.w3[4][l3i], C0[u], sm.b3[2][l3i], 0, 0, 0);
            floatx4 a3 = __builtin_amdgcn_mfma_f32_16x16x32_f16(sm.w3[6][l3i], C0[u], sm.b3[3][l3i], 0, 0, 0);
            a0 = __builtin_amdgcn_mfma_f32_16x16x32_f16(sm.w3[1][l3i], C1[u], a0, 0, 0, 0);
            a1 = __builtin_amdgcn_mfma_f32_16x16x32_f16(sm.w3[3][l3i], C1[u], a1, 0, 0, 0);
            a2 = __builtin_amdgcn_mfma_f32_16x16x32_f16(sm.w3[5][l3i], C1[u], a2, 0, 0, 0);
            a3 = __builtin_amdgcn_mfma_f32_16x16x32_f16(sm.w3[7][l3i], C1[u], a3, 0, 0, 0);
            D0[u] = act8(a0, a2);
            D1[u] = act8(a1, a3);
        }

        // ---- layer 4 + store ----
        floatx4 a4[2];
        #pragma unroll
        for (int u = 0; u < 2; ++u) {
            a4[u] = __builtin_amdgcn_mfma_f32_16x16x32_f16(w4f[0], D0[u], a4init, 0, 0, 0);
            a4[u] = __builtin_amdgcn_mfma_f32_16x16x32_f16(w4f[1], D1[u], a4[u], 0, 0, 0);
        }
        if (q == 0) {
            out[(pair << 5) + m]      = act_rev(a4[0][0]);
            out[(pair << 5) + 16 + m] = act_rev(a4[1][0]);
        }

        xv0 = xn0; xv1 = xn1;
        pair = np;
    }
}

extern "C" void kernel_launch(void* const* d_in, const int* in_sizes, int n_in,
                              void* d_out, int out_size, void* d_ws, size_t ws_size,
                              hipStream_t stream) {
    const float* x  = (const float*)d_in[0];
    const float* W1 = (const float*)d_in[1];
    const float* b1 = (const float*)d_in[2];
    const float* W2 = (const float*)d_in[3];
    const float* b2 = (const float*)d_in[4];
    const float* W3 = (const float*)d_in[5];
    const float* b3 = (const float*)d_in[6];
    const float* W4 = (const float*)d_in[7];
    const float* b4 = (const float*)d_in[8];
    float* out = (float*)d_out;
    const int N = out_size;          // 2097152, divisible by 32

    // 2048 blocks x 8 waves = 16384 waves; 65536 tile-pairs -> 4 pairs/wave.
    // 4 resident 512-thread blocks/CU at 24.6KB LDS each.
    mlp_fused<<<dim3(2048), dim3(512), 0, stream>>>(x, W1, b1, W2, b2, W3, b3, W4, b4, out, N);
}

// Round 23
// 145.548 us; speedup vs baseline: 1.6648x; 1.6648x over previous
//
#include <hip/hip_runtime.h>

typedef _Float16 half8  __attribute__((ext_vector_type(8)));
typedef _Float16 half4v __attribute__((ext_vector_type(4)));
typedef _Float16 half2v __attribute__((ext_vector_type(2)));
typedef float    floatx4 __attribute__((ext_vector_type(4)));
typedef float    float2v __attribute__((ext_vector_type(2)));

static constexpr float INVPI = 0.3183098861837907f;  // weights pre-scaled by 1/pi:
static constexpr float RLOG  = 3.82843f;             // MFMA emits 2*theta in revolutions

// Fused activation via double-angle (R16): h = E + c2*(F + G*c2), c2=cos(2theta).
// Tail in packed f16 (R20-verified). BANNED by measurement: f32 pk_fma asm
// (R17/R18 numerics), poly activation (R8/R14 slower), 2-tile jam (R15 flat,
// R21 spilled at (512,8)), biases in regs (R12 spill).
static constexpr double RD = (double)RLOG;
static constexpr double AD = RD*RD/4.0 - RD*RD*RD/16.0;
static constexpr double BD = -RD*RD/4.0 + RD*RD*RD/8.0;
static constexpr double DD = -RD*RD*RD/16.0;
static constexpr float ACT_E = (float)(AD + BD/2.0 + DD/4.0);   //  0.955347
static constexpr float ACT_F = (float)((BD + DD)/2.0);          // -0.078584
static constexpr float ACT_G = (float)(DD/4.0);                 // -0.876763

__device__ __forceinline__ float act_rev(float a2) {   // f32: final output only
    float c = __builtin_amdgcn_cosf(a2);
    float t = __builtin_fmaf(ACT_G, c, ACT_F);
    return __builtin_fmaf(c, t, ACT_E);
}

// Two C-frags (tiles t, t+2) -> next-layer B-frag directly.
// Per 8 values: 8 v_cos + 4 cvt_pkrtz + 8 v_pk_fma_f16.
__device__ __forceinline__ half8 act8(floatx4 a, floatx4 b) {
    const half2v Gh = {(_Float16)ACT_G, (_Float16)ACT_G};
    const half2v Fh = {(_Float16)ACT_F, (_Float16)ACT_F};
    const half2v Eh = {(_Float16)ACT_E, (_Float16)ACT_E};
    half2v c0 = __builtin_bit_cast(half2v, __builtin_amdgcn_cvt_pkrtz(
                    __builtin_amdgcn_cosf(a[0]), __builtin_amdgcn_cosf(a[1])));
    half2v c1 = __builtin_bit_cast(half2v, __builtin_amdgcn_cvt_pkrtz(
                    __builtin_amdgcn_cosf(a[2]), __builtin_amdgcn_cosf(a[3])));
    half2v c2 = __builtin_bit_cast(half2v, __builtin_amdgcn_cvt_pkrtz(
                    __builtin_amdgcn_cosf(b[0]), __builtin_amdgcn_cosf(b[1])));
    half2v c3 = __builtin_bit_cast(half2v, __builtin_amdgcn_cvt_pkrtz(
                    __builtin_amdgcn_cosf(b[2]), __builtin_amdgcn_cosf(b[3])));
    half2v t0 = __builtin_elementwise_fma(c0, Gh, Fh);
    half2v t1 = __builtin_elementwise_fma(c1, Gh, Fh);
    half2v t2 = __builtin_elementwise_fma(c2, Gh, Fh);
    half2v t3 = __builtin_elementwise_fma(c3, Gh, Fh);
    half2v h0 = __builtin_elementwise_fma(c0, t0, Eh);
    half2v h1 = __builtin_elementwise_fma(c1, t1, Eh);
    half2v h2 = __builtin_elementwise_fma(c2, t2, Eh);
    half2v h3 = __builtin_elementwise_fma(c3, t3, Eh);
    half4v lo = __builtin_shufflevector(h0, h1, 0, 1, 2, 3);
    half4v hi = __builtin_shufflevector(h2, h3, 0, 1, 2, 3);
    return __builtin_shufflevector(lo, hi, 0, 1, 2, 3, 4, 5, 6, 7);
}

// Per-block LDS weight cache (R9/R11-proven; biases stay in LDS).
// R11/R16/R20 config exactly: 512-thread block, 4 resident blocks/CU, grid 2048.
struct SMem {
    half8   w2[8][64];   // [(t*2+c)][lane]
    half8   w3[8][64];
    floatx4 b2[4][64];   // [t][lane]
    floatx4 b3[4][64];
};

__global__ __launch_bounds__(512, 8) void mlp_fused(
    const float* __restrict__ x,
    const float* __restrict__ W1, const float* __restrict__ b1,
    const float* __restrict__ W2, const float* __restrict__ b2,
    const float* __restrict__ W3, const float* __restrict__ b3,
    const float* __restrict__ W4, const float* __restrict__ b4,
    float* __restrict__ out, int N)
{
    __shared__ SMem sm;
    const int lane = threadIdx.x & 63;
    const int wib  = threadIdx.x >> 6;   // 0..7
    const int m    = lane & 15;   // sample / C col / A row
    const int q    = lane >> 4;   // quad
    const float s  = INVPI;      // all layers: 1/pi scaling (double-angle form)
    const floatx4 zero4 = {0.0f, 0.0f, 0.0f, 0.0f};

    // ---- in-register persistent frags (small): L1 and L4 ----
    // L1 A-frag (tile t), lanes q==0: [w0h, w0h, w0l, w1h, w1h, w1l, b1h, b1l]
    half8 w1f[4];
    #pragma unroll
    for (int t = 0; t < 4; ++t) {
        half8 v = {};
        if (q == 0) {
            const int n = 16 * t + m;
            float w0 = W1[2*n] * s, w1 = W1[2*n+1] * s, bb = b1[n] * s;
            _Float16 w0h = (_Float16)w0; float w0l = w0 - (float)w0h;
            _Float16 w1h = (_Float16)w1; float w1l = w1 - (float)w1h;
            _Float16 bh  = (_Float16)bb; float bl  = bb - (float)bh;
            v[0] = w0h; v[1] = w0h; v[2] = (_Float16)w0l;
            v[3] = w1h; v[4] = w1h; v[5] = (_Float16)w1l;
            v[6] = bh;  v[7] = (_Float16)bl;
        }
        w1f[t] = v;
    }
    // L4 A-frag: only out-row m==0 real; sigma column permutation
    //   sigma: k-slot (c,q,j) -> neuron (j<4 ? 16c+4q+j : 16(c+2)+4q+j-4)
    half8 w4f[2] = {half8{}, half8{}};
    if (m == 0) {
        #pragma unroll
        for (int c = 0; c < 2; ++c)
            #pragma unroll
            for (int j = 0; j < 8; ++j) {
                int nu = (j < 4) ? (16 * c + 4 * q + j) : (16 * (c + 2) + 4 * q + j - 4);
                w4f[c][j] = (_Float16)(W4[nu] * s);
            }
    }
    floatx4 a4init = zero4;
    if (q == 0) a4init[0] = b4[0] * s;       // C row 0 = (q=0, r=0)

    // ---- wave-split LDS prep (sigma-permuted columns), one barrier ----
    if (wib == 0) {
        #pragma unroll
        for (int t = 0; t < 4; ++t) {
            const float* r2 = W2 + (16 * t + m) * 64;
            #pragma unroll
            for (int c = 0; c < 2; ++c) {
                floatx4 lo2 = *(const floatx4*)(r2 + 16 * c + 4 * q);
                floatx4 hi2 = *(const floatx4*)(r2 + 16 * (c + 2) + 4 * q);
                half8 v2;
                #pragma unroll
                for (int j = 0; j < 4; ++j) {
                    v2[j]     = (_Float16)(lo2[j] * s);
                    v2[4 + j] = (_Float16)(hi2[j] * s);
                }
                sm.w2[t * 2 + c][lane] = v2;
            }
        }
    } else if (wib == 1) {
        #pragma unroll
        for (int t = 0; t < 4; ++t) {
            const float* r3 = W3 + (16 * t + m) * 64;
            #pragma unroll
            for (int c = 0; c < 2; ++c) {
                floatx4 lo3 = *(const floatx4*)(r3 + 16 * c + 4 * q);
                floatx4 hi3 = *(const floatx4*)(r3 + 16 * (c + 2) + 4 * q);
                half8 v3;
                #pragma unroll
                for (int j = 0; j < 4; ++j) {
                    v3[j]     = (_Float16)(lo3[j] * s);
                    v3[4 + j] = (_Float16)(hi3[j] * s);
                }
                sm.w3[t * 2 + c][lane] = v3;
            }
        }
    } else if (wib == 2) {
        #pragma unroll
        for (int t = 0; t < 4; ++t) {
            sm.b2[t][lane] = *(const floatx4*)(b2 + 16 * t + 4 * q) * s;
            sm.b3[t][lane] = *(const floatx4*)(b3 + 16 * t + 4 * q) * s;
        }
    }
    __syncthreads();

    const int ntiles = N >> 4;
    const int nwaves = (gridDim.x * blockDim.x) >> 6;
    const int gwave  = (int)(blockIdx.x * blockDim.x + threadIdx.x) >> 6;
    const float2* __restrict__ x2 = (const float2*)x;

    int tile = gwave;
    float2 xv = x2[(tile << 4) + m];          // 1-ahead x prefetch
    while (tile < ntiles) {
        const int nt = tile + nwaves;
        float2 xnext;
        if (nt < ntiles) xnext = x2[(nt << 4) + m];

        // L1 B-frag (lanes q==0): [xh, xl, xh, yh, yl, yh, 1, 1]
        half8 xa = {};
        if (q == 0) {
            _Float16 xh = (_Float16)xv.x; float xl = xv.x - (float)xh;
            _Float16 yh = (_Float16)xv.y; float yl = xv.y - (float)yh;
            xa[0] = xh; xa[1] = (_Float16)xl; xa[2] = xh;
            xa[3] = yh; xa[4] = (_Float16)yl; xa[5] = yh;
            xa[6] = (_Float16)1.0f; xa[7] = (_Float16)1.0f;
        }

        // ---- layer 1 (in-register frags) ----
        floatx4 a0 = __builtin_amdgcn_mfma_f32_16x16x32_f16(w1f[0], xa, zero4, 0, 0, 0);
        floatx4 a1 = __builtin_amdgcn_mfma_f32_16x16x32_f16(w1f[1], xa, zero4, 0, 0, 0);
        floatx4 a2 = __builtin_amdgcn_mfma_f32_16x16x32_f16(w1f[2], xa, zero4, 0, 0, 0);
        floatx4 a3 = __builtin_amdgcn_mfma_f32_16x16x32_f16(w1f[3], xa, zero4, 0, 0, 0);
        half8 B0 = act8(a0, a2);
        half8 B1 = act8(a1, a3);

        // Opaque zero per layer: defeats LICM (else the LDS reads hoist back
        // into ~128 live regs and spill) AND staggers reads so peak staging
        // is one layer's worth.
        int z2 = 0; asm volatile("" : "+v"(z2));
        const int l2i = lane + z2;
        a0 = __builtin_amdgcn_mfma_f32_16x16x32_f16(sm.w2[0][l2i], B0, sm.b2[0][l2i], 0, 0, 0);
        a1 = __builtin_amdgcn_mfma_f32_16x16x32_f16(sm.w2[2][l2i], B0, sm.b2[1][l2i], 0, 0, 0);
        a2 = __builtin_amdgcn_mfma_f32_16x16x32_f16(sm.w2[4][l2i], B0, sm.b2[2][l2i], 0, 0, 0);
        a3 = __builtin_amdgcn_mfma_f32_16x16x32_f16(sm.w2[6][l2i], B0, sm.b2[3][l2i], 0, 0, 0);
        a0 = __builtin_amdgcn_mfma_f32_16x16x32_f16(sm.w2[1][l2i], B1, a0, 0, 0, 0);
        a1 = __builtin_amdgcn_mfma_f32_16x16x32_f16(sm.w2[3][l2i], B1, a1, 0, 0, 0);
        a2 = __builtin_amdgcn_mfma_f32_16x16x32_f16(sm.w2[5][l2i], B1, a2, 0, 0, 0);
        a3 = __builtin_amdgcn_mfma_f32_16x16x32_f16(sm.w2[7][l2i], B1, a3, 0, 0, 0);
        half8 C0 = act8(a0, a2);
        half8 C1 = act8(a1, a3);

        int z3 = 0; asm volatile("" : "+v"(z3));
        const int l3i = lane + z3;
        a0 = __builtin_amdgcn_mfma_f32_16x16x32_f16(sm.w3[0][l3i], C0, sm.b3[0][l3i], 0, 0, 0);
        a1 = __builtin_amdgcn_mfma_f32_16x16x32_f16(sm.w3[2][l3i], C0, sm.b3[1][l3i], 0, 0, 0);
        a2 = __builtin_amdgcn_mfma_f32_16x16x32_f16(sm.w3[4][l3i], C0, sm.b3[2][l3i], 0, 0, 0);
        a3 = __builtin_amdgcn_mfma_f32_16x16x32_f16(sm.w3[6][l3i], C0, sm.b3[3][l3i], 0, 0, 0);
        a0 = __builtin_amdgcn_mfma_f32_16x16x32_f16(sm.w3[1][l3i], C1, a0, 0, 0, 0);
        a1 = __builtin_amdgcn_mfma_f32_16x16x32_f16(sm.w3[3][l3i], C1, a1, 0, 0, 0);
        a2 = __builtin_amdgcn_mfma_f32_16x16x32_f16(sm.w3[5][l3i], C1, a2, 0, 0, 0);
        a3 = __builtin_amdgcn_mfma_f32_16x16x32_f16(sm.w3[7][l3i], C1, a3, 0, 0, 0);
        half8 D0 = act8(a0, a2);
        half8 D1 = act8(a1, a3);

        // ---- layer 4 + store ----
        floatx4 a4 = __builtin_amdgcn_mfma_f32_16x16x32_f16(w4f[0], D0, a4init, 0, 0, 0);
        a4 = __builtin_amdgcn_mfma_f32_16x16x32_f16(w4f[1], D1, a4, 0, 0, 0);
        if (q == 0)
            out[(tile << 4) + m] = act_rev(a4[0]);

        xv = xnext;
        tile = nt;
    }
}

extern "C" void kernel_launch(void* const* d_in, const int* in_sizes, int n_in,
                              void* d_out, int out_size, void* d_ws, size_t ws_size,
                              hipStream_t stream) {
    const float* x  = (const float*)d_in[0];
    const float* W1 = (const float*)d_in[1];
    const float* b1 = (const float*)d_in[2];
    const float* W2 = (const float*)d_in[3];
    const float* b2 = (const float*)d_in[4];
    const float* W3 = (const float*)d_in[5];
    const float* b3 = (const float*)d_in[6];
    const float* W4 = (const float*)d_in[7];
    const float* b4 = (const float*)d_in[8];
    float* out = (float*)d_out;
    const int N = out_size;          // 2097152, divisible by 16

    // R20-best config: 2048 blocks x 8 waves = 16384 waves; 131072 tiles ->
    // 8 tiles/wave. 4 resident 512-thread blocks/CU at 24.6KB LDS each.
    mlp_fused<<<dim3(2048), dim3(512), 0, stream>>>(x, W1, b1, W2, b2, W3, b3, W4, b4, out, N);
}